// Round 7
// baseline (162.561 us; speedup 1.0000x reference)
//
#include <hip/hip_runtime.h>
#include <cstdint>
#include <cfloat>
#include <cmath>

#define NPTS 65536
#define NB 16
#define NS 20
#define KK 10
#define FPB 16      // blocks per batch
#define NSm1 (NS - 1)

struct InitIdx { int idx[NB]; };

#define CSWAP(a, b) { float _lo = fminf(a, b), _hi = fmaxf(a, b); a = _lo; b = _hi; }

// ---------------- Fused FPS + kNN + repulsion (exact JAX semantics) ---------
// 256 blocks (16/batch) x 1024 threads; each thread owns 4 CONTIGUOUS points
// (3x float4 = 48B aligned load), coords + running-min in registers for the
// whole kernel. Per step s:
//   d[q] = squared dist of my 4 points to centroid s  (shared by FPS and kNN)
//   FPS (s<19): dm=min(dm,d); block argmax -> wave1 publishes packed u64 key
//     (fbits(val)<<32 | ~idx : max val, tie -> smallest idx = JAX argmax)
//     to IC via relaxed agent store; after B2 wave1 polls all 16 keys.
//   kNN: sort4 + wave-level 11-pop -> s_top; after B2 wave0 merges 16x11 and
//     publishes 11 self-contained nonzero u32 keys (fbits(sq)+1, monotone).
//   The kNN merge (wave0) overlaps the fps poll (wave1) - sync slack reuse.
// Tail: block j merges seeds {j, j+16} (poll 176 keys, 11-pop, repulsion,
// atomicAdd). The point cloud is never re-read: kNN rides the FPS registers.
__global__ __launch_bounds__(1024) void fused_kernel(const float* __restrict__ pcs,
                                                     unsigned long long* __restrict__ fkey,
                                                     unsigned int* __restrict__ kslot,
                                                     float* __restrict__ out,
                                                     InitIdx init) {
    const int u   = blockIdx.x;
    const int xcd = u & 7;              // XCD heuristic (perf-only)
    const int k   = u >> 3;             // 0..31
    const int b   = 2 * xcd + (k >> 4); // batch
    const int j   = k & 15;             // block-in-batch
    const int t   = threadIdx.x;
    const int lane = t & 63;
    const int w    = t >> 6;            // wave 0..15
    const float* __restrict__ base = pcs + (size_t)b * NPTS * 3;
    const int pbase = j * 4096 + t * 4; // 4 contiguous points per thread

    // one-time vectorized coord load: 48 B = 3 x float4 (16B-aligned)
    const float4* q4 = reinterpret_cast<const float4*>(base + (size_t)pbase * 3);
    float4 A = q4[0], Bv = q4[1], Cv = q4[2];
    float x[4] = { A.x, A.w, Bv.z, Cv.y };
    float y[4] = { A.y, Bv.x, Bv.w, Cv.z };
    float z[4] = { A.z, Bv.y, Cv.x, Cv.w };
    float dm[4] = { 1e10f, 1e10f, 1e10f, 1e10f };

    __shared__ float s_val[16];
    __shared__ int   s_idx[16];
    __shared__ float s_top[16][11];
    __shared__ int   s_far;

    int far = init.idx[b];

    for (int s = 0; s < NS; ++s) {
        const float* c = base + (size_t)far * 3;       // uniform, cached
        const float cx = c[0], cy = c[1], cz = c[2];

        float d[4];
#pragma unroll
        for (int q = 0; q < 4; ++q) {
            // match XLA: rounded sub/mul, sequential adds, NO fma contraction
            float dx = __fsub_rn(x[q], cx);
            float dy = __fsub_rn(y[q], cy);
            float dz = __fsub_rn(z[q], cz);
            d[q] = __fadd_rn(__fadd_rn(__fmul_rn(dx, dx), __fmul_rn(dy, dy)),
                             __fmul_rn(dz, dz));
        }

        if (s < NSm1) {
            float bestv = -1.0f;
            int   besti = 0;
#pragma unroll
            for (int q = 0; q < 4; ++q) {
                dm[q] = fminf(dm[q], d[q]);
                // q ascending = index ascending; strict > = first occurrence
                if (dm[q] > bestv) { bestv = dm[q]; besti = pbase + q; }
            }
#pragma unroll
            for (int off = 32; off >= 1; off >>= 1) {
                float ov = __shfl_down(bestv, off);
                int   oi = __shfl_down(besti, off);
                if (ov > bestv || (ov == bestv && oi < besti)) { bestv = ov; besti = oi; }
            }
            if (lane == 0) { s_val[w] = bestv; s_idx[w] = besti; }
        }
        __syncthreads();                               // B1

        // ---- wave 1: publish fps partial key early (parallel 16-way reduce)
        if (w == 1 && s < NSm1) {
            unsigned long long kv = 0ULL;
            if (lane < 16) {
                kv = ((unsigned long long)__float_as_uint(s_val[lane]) << 32) |
                     (unsigned long long)(0xFFFFFFFFu - (unsigned int)s_idx[lane]);
            }
#pragma unroll
            for (int off = 8; off >= 1; off >>= 1) {
                unsigned int lo = (unsigned int)kv, hi = (unsigned int)(kv >> 32);
                unsigned int olo = (unsigned int)__shfl_xor((int)lo, off);
                unsigned int ohi = (unsigned int)__shfl_xor((int)hi, off);
                unsigned long long o = ((unsigned long long)ohi << 32) | olo;
                if (o > kv) kv = o;
            }
            if (lane == 0)
                __hip_atomic_store(&fkey[(size_t)(b * NS + s) * FPB + j], kv,
                                   __ATOMIC_RELAXED, __HIP_MEMORY_SCOPE_AGENT);
        }

        // ---- all waves: per-wave top-11 of this seed's distances ----------
        {
            float c4[4] = { d[0], d[1], d[2], d[3] };
            CSWAP(c4[0], c4[1]); CSWAP(c4[2], c4[3]);
            CSWAP(c4[0], c4[2]); CSWAP(c4[1], c4[3]); CSWAP(c4[1], c4[2]);
#pragma unroll
            for (int r = 0; r < 11; ++r) {
                float v = c4[0];
#pragma unroll
                for (int off = 32; off >= 1; off >>= 1) v = fminf(v, __shfl_xor(v, off));
                unsigned long long m = __ballot(c4[0] == v);
                if (lane == (int)__ffsll(m) - 1) {      // pop exactly one copy
                    c4[0] = c4[1]; c4[1] = c4[2]; c4[2] = c4[3]; c4[3] = FLT_MAX;
                }
                if (lane == 0) s_top[w][r] = v;
            }
        }
        __syncthreads();                               // B2

        if (w == 0) {
            // ---- block merge 16x11 -> 11, publish (overlaps wave1's poll) --
            const float* flat = &s_top[0][0];
            float a0 = flat[lane];
            float a1 = flat[lane + 64];
            float a2 = (lane + 128 < 176) ? flat[lane + 128] : FLT_MAX;
            float keep = 0.0f;
#pragma unroll
            for (int r = 0; r < 11; ++r) {
                float mymin = fminf(a0, fminf(a1, a2));
                float v = mymin;
#pragma unroll
                for (int off = 32; off >= 1; off >>= 1) v = fminf(v, __shfl_xor(v, off));
                unsigned long long m = __ballot(mymin == v);
                if (lane == (int)__ffsll(m) - 1) {
                    if (a0 == v)      a0 = FLT_MAX;
                    else if (a1 == v) a1 = FLT_MAX;
                    else              a2 = FLT_MAX;
                }
                if (lane == r) keep = v;               // lane r keeps round r
            }
            if (lane < 11) {
                // key = fbits(sq)+1: nonzero, strictly order-preserving (sq>=0)
                unsigned int key = __float_as_uint(keep) + 1u;
                __hip_atomic_store(
                    &kslot[((size_t)(b * NS + s) * FPB + j) * 11 + lane], key,
                    __ATOMIC_RELAXED, __HIP_MEMORY_SCOPE_AGENT);
            }
        } else if (w == 1 && s < NSm1) {
            // ---- fps poll: 16 keys (x4 redundant lanes, coalesced loads) ---
            unsigned long long* fp = fkey + (size_t)(b * NS + s) * FPB;
            unsigned long long v;
            do {
                v = __hip_atomic_load(&fp[lane & 15], __ATOMIC_RELAXED,
                                      __HIP_MEMORY_SCOPE_AGENT);
            } while (__any(v == 0ULL));
#pragma unroll
            for (int off = 32; off >= 1; off >>= 1) {
                unsigned int lo = (unsigned int)v, hi = (unsigned int)(v >> 32);
                unsigned int olo = (unsigned int)__shfl_xor((int)lo, off);
                unsigned int ohi = (unsigned int)__shfl_xor((int)hi, off);
                unsigned long long o = ((unsigned long long)ohi << 32) | olo;
                if (o > v) v = o;
            }
            if (lane == 0)
                s_far = (int)(0xFFFFFFFFu - (unsigned int)(v & 0xFFFFFFFFull));
        }
        __syncthreads();                               // B3
        if (s < NSm1) far = s_far;
    }

    // ---- tail: block j merges seeds {j, j+16}: poll 176 keys, top-11, loss -
    for (int s2 = j; s2 < NS; s2 += FPB) {
        if (w == 0) {
            const unsigned int* sl = kslot + (size_t)(b * NS + s2) * FPB * 11;
            unsigned int k0 = 0, k1 = 0, k2 = (lane + 128 < 176) ? 0u : 1u;
            do {
                if (k0 == 0) k0 = __hip_atomic_load(&sl[lane], __ATOMIC_RELAXED,
                                                    __HIP_MEMORY_SCOPE_AGENT);
                if (k1 == 0) k1 = __hip_atomic_load(&sl[lane + 64], __ATOMIC_RELAXED,
                                                    __HIP_MEMORY_SCOPE_AGENT);
                if (k2 == 0) k2 = __hip_atomic_load(&sl[lane + 128], __ATOMIC_RELAXED,
                                                    __HIP_MEMORY_SCOPE_AGENT);
            } while (__any(k0 == 0 || k1 == 0 || k2 == 0));
            float a0 = __uint_as_float(k0 - 1u);
            float a1 = __uint_as_float(k1 - 1u);
            float a2 = (lane + 128 < 176) ? __uint_as_float(k2 - 1u) : FLT_MAX;

            const float HH = (float)(0.01 * 0.01);     // JAX weak-typed H*H
            float acc = 0.0f;
#pragma unroll
            for (int r = 0; r < 11; ++r) {
                float mymin = fminf(a0, fminf(a1, a2));
                float v = mymin;
#pragma unroll
                for (int off = 32; off >= 1; off >>= 1) v = fminf(v, __shfl_xor(v, off));
                unsigned long long m = __ballot(mymin == v);
                if (lane == (int)__ffsll(m) - 1) {
                    if (a0 == v)      a0 = FLT_MAX;
                    else if (a1 == v) a1 = FLT_MAX;
                    else              a2 = FLT_MAX;
                }
                if (lane == 0 && r >= 1) {             // r==0 is self (dist 0)
                    float sq = v;
                    float dd = (sq == 0.0f) ? 0.0f : __fsqrt_rn(sq);
                    float q2 = __fmul_rn(dd, dd);
                    float wt = expf(__fdiv_rn(-q2, HH));
                    acc = __fadd_rn(acc, -__fmul_rn(dd, wt));
                }
            }
            if (lane == 0) atomicAdd(out, acc * 0.0625f);   // mean over B=16
        }
    }
}

// ---------------- Host: JAX threefry2x32 (partitionable mode) ---------------
static inline uint32_t rotl32(uint32_t x, uint32_t d) { return (x << d) | (x >> (32 - d)); }

static void tf2x32(uint32_t k0, uint32_t k1, uint32_t x0, uint32_t x1,
                   uint32_t& y0, uint32_t& y1) {
    const uint32_t ks[3] = { k0, k1, k0 ^ k1 ^ 0x1BD11BDAu };
    const uint32_t rotA[4] = { 13, 15, 26, 6 };
    const uint32_t rotB[4] = { 17, 29, 16, 24 };
    uint32_t v0 = x0 + ks[0], v1 = x1 + ks[1];
    for (int i = 0; i < 5; ++i) {
        const uint32_t* rot = (i % 2 == 0) ? rotA : rotB;
        for (int j = 0; j < 4; ++j) {
            v0 += v1;
            v1 = rotl32(v1, rot[j]);
            v1 ^= v0;
        }
        v0 += ks[(i + 1) % 3];
        v1 += ks[(i + 2) % 3] + (uint32_t)(i + 1);
    }
    y0 = v0; y1 = v1;
}

extern "C" void kernel_launch(void* const* d_in, const int* in_sizes, int n_in,
                              void* d_out, int out_size, void* d_ws, size_t ws_size,
                              hipStream_t stream) {
    const float* pcs = (const float*)d_in[0];
    float* out = (float*)d_out;

    // ws: [0, 40960) fps keys u64 [16][20][16]; [40960, 266240) knn slots
    //     u32 [16][20][16][11]
    unsigned long long* fkey = (unsigned long long*)d_ws;
    unsigned int* kslot      = (unsigned int*)((char*)d_ws + 40960);

    // jax.random.key(1) -> threefry key (0,1), partitionable mode:
    //   split foldlike: k2 = threefry((0,1),(0,1)) both words
    //   random_bits: counters (0,i), out = y0 ^ y1; randint span 2^16 -> mask
    uint32_t k2_0, k2_1;
    tf2x32(0u, 1u, 0u, 1u, k2_0, k2_1);
    InitIdx init;
    for (int i = 0; i < NB; ++i) {
        uint32_t y0, y1;
        tf2x32(k2_0, k2_1, 0u, (uint32_t)i, y0, y1);
        init.idx[i] = (int)((y0 ^ y1) & 0xFFFFu);
    }

    hipMemsetAsync(d_ws, 0, 266240, stream);   // keys+slots zeroed every call
    hipMemsetAsync(d_out, 0, sizeof(float), stream);

    hipLaunchKernelGGL(fused_kernel, dim3(NB * FPB), dim3(1024), 0, stream,
                       pcs, fkey, kslot, out, init);
}

// Round 8
// 100.174 us; speedup vs baseline: 1.6228x; 1.6228x over previous
//
#include <hip/hip_runtime.h>
#include <cstdint>
#include <cfloat>
#include <cmath>

#define NPTS 65536
#define NB 16
#define NS 20
#define KK 10
#define FPB 16      // FPS blocks per batch
#define NSm1 (NS - 1)

struct InitIdx { int idx[NB]; };

static __device__ __forceinline__ unsigned long long
agent_ld(const unsigned long long* p) {
    return __hip_atomic_load(p, __ATOMIC_RELAXED, __HIP_MEMORY_SCOPE_AGENT);
}

// ---------------- Kernel 1: distributed FPS (exact JAX semantics) -----------
// 256 blocks (16/batch) x 1024 threads; 4 CONTIGUOUS points/thread loaded once
// as 3x float4, coords + running-min in registers the whole kernel.
// Per step: compute d, dm=min(dm,d), wave argmax (strict >, tie -> smaller
// index = JAX first-occurrence), B1, wave0: parallel 16-lane block reduce ->
// lane0 publishes packed u64 key (fbits(val)<<32 | ~idx, monotone, nonzero)
// via relaxed agent store to IC; wave0 then polls the batch's 16 keys with a
// 3-DEEP pipelined load loop (sampling interval ~L/3 instead of L, cutting
// detect latency + cross-block jitter), shuffle-max-reduces, B2.
__global__ __launch_bounds__(1024) void fps_kernel(const float* __restrict__ pcs,
                                                   int* __restrict__ seeds,
                                                   unsigned long long* __restrict__ fkey,
                                                   InitIdx init) {
    const int u   = blockIdx.x;
    const int xcd = u & 7;              // XCD heuristic (perf-only)
    const int k   = u >> 3;             // 0..31
    const int b   = 2 * xcd + (k >> 4); // batch
    const int j   = k & 15;             // block-in-batch
    const int t   = threadIdx.x;
    const int lane = t & 63;
    const int w    = t >> 6;
    const float* __restrict__ base = pcs + (size_t)b * NPTS * 3;
    const int pbase = j * 4096 + t * 4; // 4 contiguous points per thread

    const float4* q4 = reinterpret_cast<const float4*>(base + (size_t)pbase * 3);
    float4 A = q4[0], Bv = q4[1], Cv = q4[2];
    float x[4] = { A.x, A.w, Bv.z, Cv.y };
    float y[4] = { A.y, Bv.x, Bv.w, Cv.z };
    float z[4] = { A.z, Bv.y, Cv.x, Cv.w };
    float dm[4] = { 1e10f, 1e10f, 1e10f, 1e10f };

    __shared__ float s_val[16];
    __shared__ int   s_idx[16];
    __shared__ int   s_far;

    int far = init.idx[b];

    for (int s = 0; s < NS; ++s) {
        if (j == 0 && t == 0) seeds[b * NS + s] = far;   // seed s BEFORE update
        if (s == NSm1) break;                            // last update unused

        const float* c = base + (size_t)far * 3;         // uniform, cached
        const float cx = c[0], cy = c[1], cz = c[2];

        float bestv = -1.0f;
        int   besti = 0;
#pragma unroll
        for (int q = 0; q < 4; ++q) {
            // match XLA: rounded sub/mul, sequential adds, NO fma contraction
            float dx = __fsub_rn(x[q], cx);
            float dy = __fsub_rn(y[q], cy);
            float dz = __fsub_rn(z[q], cz);
            float d  = __fadd_rn(__fadd_rn(__fmul_rn(dx, dx), __fmul_rn(dy, dy)),
                                 __fmul_rn(dz, dz));
            dm[q] = fminf(dm[q], d);
            // q ascending = index ascending; strict > keeps first occurrence
            if (dm[q] > bestv) { bestv = dm[q]; besti = pbase + q; }
        }
#pragma unroll
        for (int off = 32; off >= 1; off >>= 1) {
            float ov = __shfl_down(bestv, off);
            int   oi = __shfl_down(besti, off);
            if (ov > bestv || (ov == bestv && oi < besti)) { bestv = ov; besti = oi; }
        }
        if (lane == 0) { s_val[w] = bestv; s_idx[w] = besti; }
        __syncthreads();                                 // B1

        if (w == 0) {
            // parallel 16-lane block reduce -> packed key -> publish
            unsigned long long kv = 0ULL;
            if (lane < 16) {
                kv = ((unsigned long long)__float_as_uint(s_val[lane]) << 32) |
                     (unsigned long long)(0xFFFFFFFFu - (unsigned int)s_idx[lane]);
            }
#pragma unroll
            for (int off = 8; off >= 1; off >>= 1) {
                unsigned int lo = (unsigned int)kv, hi = (unsigned int)(kv >> 32);
                unsigned int olo = (unsigned int)__shfl_xor((int)lo, off);
                unsigned int ohi = (unsigned int)__shfl_xor((int)hi, off);
                unsigned long long o = ((unsigned long long)ohi << 32) | olo;
                if (o > kv) kv = o;
            }
            unsigned long long* fp = fkey + (size_t)(b * NS + s) * FPB;
            if (lane == 0)
                __hip_atomic_store(&fp[j], kv, __ATOMIC_RELAXED,
                                   __HIP_MEMORY_SCOPE_AGENT);

            // 3-deep pipelined poll of the 16 slots (lane l watches slot l&15)
            const unsigned long long* sl = fp + (lane & 15);
            unsigned long long p0 = agent_ld(sl);
            unsigned long long p1 = agent_ld(sl);
            unsigned long long p2 = agent_ld(sl);
            unsigned long long v;
            for (;;) {
                if (!__any(p0 == 0ULL)) { v = p0; break; }
                p0 = agent_ld(sl);
                if (!__any(p1 == 0ULL)) { v = p1; break; }
                p1 = agent_ld(sl);
                if (!__any(p2 == 0ULL)) { v = p2; break; }
                p2 = agent_ld(sl);
            }
#pragma unroll
            for (int off = 32; off >= 1; off >>= 1) {
                unsigned int lo = (unsigned int)v, hi = (unsigned int)(v >> 32);
                unsigned int olo = (unsigned int)__shfl_xor((int)lo, off);
                unsigned int ohi = (unsigned int)__shfl_xor((int)hi, off);
                unsigned long long o = ((unsigned long long)ohi << 32) | olo;
                if (o > v) v = o;
            }
            if (lane == 0)
                s_far = (int)(0xFFFFFFFFu - (unsigned int)(v & 0xFFFFFFFFull));
        }
        __syncthreads();                                 // B2
        far = s_far;
    }
}

// ---------------- Kernel 2: per-seed 11 smallest distances + repulsion ------
// One block (1024 thr) per (batch, seed), XCD-mapped (batch's 20 blocks on one
// XCD -> reads L2-served). 4 CONTIGUOUS points/thread per iteration via
// 3x float4 (48 coalesced VMEM instr total vs 192 scalar). Per-thread sorted
// top-11 of squared distances, wave-level 11-pop, single-wave final merge.
// sqrt is monotone -> selection on sq == selection on dist.
__global__ __launch_bounds__(1024) void knn_kernel(const float* __restrict__ pcs,
                                                   const int* __restrict__ seeds,
                                                   float* __restrict__ out) {
    const int u   = blockIdx.x;        // 0..319
    const int xcd = u & 7;
    const int k   = u >> 3;            // 0..39
    const int b   = 2 * xcd + (k & 1);
    const int s   = k >> 1;            // 0..19
    const int t = threadIdx.x;
    const int lane = t & 63;
    const int w = t >> 6;              // wave id 0..15
    const float* __restrict__ base = pcs + (size_t)b * NPTS * 3;
    const int sidx = seeds[b * NS + s];
    const float cx = base[(size_t)sidx * 3 + 0];
    const float cy = base[(size_t)sidx * 3 + 1];
    const float cz = base[(size_t)sidx * 3 + 2];

    float lst[11];
#pragma unroll
    for (int jj = 0; jj < 11; ++jj) lst[jj] = FLT_MAX;

    for (int i = 0; i < 16; ++i) {
        const int pbase = i * 4096 + t * 4;
        const float4* q4 = reinterpret_cast<const float4*>(base + (size_t)pbase * 3);
        float4 A = q4[0], Bv = q4[1], Cv = q4[2];
        float px[4] = { A.x, A.w, Bv.z, Cv.y };
        float py[4] = { A.y, Bv.x, Bv.w, Cv.z };
        float pz[4] = { A.z, Bv.y, Cv.x, Cv.w };
#pragma unroll
        for (int q = 0; q < 4; ++q) {
            float dx = __fsub_rn(px[q], cx);
            float dy = __fsub_rn(py[q], cy);
            float dz = __fsub_rn(pz[q], cz);
            float sq = __fadd_rn(__fadd_rn(__fmul_rn(dx, dx), __fmul_rn(dy, dy)),
                                 __fmul_rn(dz, dz));
            if (sq < lst[10]) {
                lst[10] = sq;
#pragma unroll
                for (int jj = 10; jj > 0; --jj) {
                    float a = lst[jj - 1], c = lst[jj];
                    lst[jj - 1] = fminf(a, c);
                    lst[jj]     = fmaxf(a, c);
                }
            }
        }
    }

    // ---- wave-level top-11: 11 rounds of (wave-min of heads, pop one copy) --
    __shared__ float s_top[16][11];
    for (int r = 0; r < 11; ++r) {
        float v = lst[0];
#pragma unroll
        for (int off = 32; off >= 1; off >>= 1) v = fminf(v, __shfl_xor(v, off));
        unsigned long long m = __ballot(lst[0] == v);
        if (lane == (int)__ffsll(m) - 1) {     // pop exactly one copy
#pragma unroll
            for (int jj = 0; jj < 10; ++jj) lst[jj] = lst[jj + 1];
            lst[10] = FLT_MAX;
        }
        if (lane == 0) s_top[w][r] = v;
    }
    __syncthreads();

    // ---- final merge: wave 0 merges 16 lists x 11 = 176 values -------------
    if (w == 0) {
        const float* flat = &s_top[0][0];
        float a0 = flat[lane];
        float a1 = flat[lane + 64];
        float a2 = (lane + 128 < 176) ? flat[lane + 128] : FLT_MAX;

        const float HH = (float)(0.01 * 0.01);   // JAX weak-typed scalar H*H
        float acc = 0.0f;
#pragma unroll
        for (int r = 0; r < 11; ++r) {
            float mymin = fminf(a0, fminf(a1, a2));
            float v = mymin;
#pragma unroll
            for (int off = 32; off >= 1; off >>= 1) v = fminf(v, __shfl_xor(v, off));
            unsigned long long m = __ballot(mymin == v);
            if (lane == (int)__ffsll(m) - 1) {
                if (a0 == v)      a0 = FLT_MAX;
                else if (a1 == v) a1 = FLT_MAX;
                else              a2 = FLT_MAX;
            }
            if (lane == 0 && r >= 1) {           // r==0 is self (dist 0)
                float sq = v;
                float d  = (sq == 0.0f) ? 0.0f : __fsqrt_rn(sq);
                float q2 = __fmul_rn(d, d);
                float wt = expf(__fdiv_rn(-q2, HH));
                acc = __fadd_rn(acc, -__fmul_rn(d, wt));
            }
        }
        if (lane == 0) atomicAdd(out, acc * 0.0625f);   // mean over B=16
    }
}

// ---------------- Host: JAX threefry2x32 (partitionable mode) ---------------
static inline uint32_t rotl32(uint32_t x, uint32_t d) { return (x << d) | (x >> (32 - d)); }

static void tf2x32(uint32_t k0, uint32_t k1, uint32_t x0, uint32_t x1,
                   uint32_t& y0, uint32_t& y1) {
    const uint32_t ks[3] = { k0, k1, k0 ^ k1 ^ 0x1BD11BDAu };
    const uint32_t rotA[4] = { 13, 15, 26, 6 };
    const uint32_t rotB[4] = { 17, 29, 16, 24 };
    uint32_t v0 = x0 + ks[0], v1 = x1 + ks[1];
    for (int i = 0; i < 5; ++i) {
        const uint32_t* rot = (i % 2 == 0) ? rotA : rotB;
        for (int j = 0; j < 4; ++j) {
            v0 += v1;
            v1 = rotl32(v1, rot[j]);
            v1 ^= v0;
        }
        v0 += ks[(i + 1) % 3];
        v1 += ks[(i + 2) % 3] + (uint32_t)(i + 1);
    }
    y0 = v0; y1 = v1;
}

extern "C" void kernel_launch(void* const* d_in, const int* in_sizes, int n_in,
                              void* d_out, int out_size, void* d_ws, size_t ws_size,
                              hipStream_t stream) {
    const float* pcs = (const float*)d_in[0];
    float* out = (float*)d_out;

    // ws: [0,1280) seeds (int); [2048, 2048+16*20*16*8=43008) fps keys (u64)
    int* seeds               = (int*)d_ws;
    unsigned long long* fkey = (unsigned long long*)((char*)d_ws + 2048);

    // jax.random.key(1) -> threefry key (0,1), partitionable mode:
    //   split foldlike: k2 = threefry((0,1),(0,1)) both words
    //   random_bits: counters (0,i), out = y0 ^ y1; randint span 2^16 -> mask
    uint32_t k2_0, k2_1;
    tf2x32(0u, 1u, 0u, 1u, k2_0, k2_1);
    InitIdx init;
    for (int i = 0; i < NB; ++i) {
        uint32_t y0, y1;
        tf2x32(k2_0, k2_1, 0u, (uint32_t)i, y0, y1);
        init.idx[i] = (int)((y0 ^ y1) & 0xFFFFu);
    }

    hipMemsetAsync(d_ws, 0, 43008, stream);   // seeds + fps keys
    hipMemsetAsync(d_out, 0, sizeof(float), stream);

    hipLaunchKernelGGL(fps_kernel, dim3(NB * FPB), dim3(1024), 0, stream,
                       pcs, seeds, fkey, init);
    hipLaunchKernelGGL(knn_kernel, dim3(NB * NS), dim3(1024), 0, stream,
                       pcs, seeds, out);
}